// Round 1
// baseline (118.702 us; speedup 1.0000x reference)
//
#include <hip/hip_runtime.h>
#include <cstdint>

#define MARGIN_F 0.2f

typedef __attribute__((ext_vector_type(8))) short sv8;   // 8 x bf16 (4 VGPRs)
typedef __attribute__((ext_vector_type(4))) float fv4;   // MFMA accumulator

// ---- round-to-nearest-even fp32 -> bf16 (bit pattern) ----
__device__ __forceinline__ unsigned short f2bf(float x) {
    unsigned u = __float_as_uint(x);
    unsigned r = (u + 0x7fffu + ((u >> 16) & 1u)) >> 16;
    return (unsigned short)r;
}

// ---- async global->LDS, 16B per lane (dest = wave-uniform base + lane*16) ----
__device__ __forceinline__ void gload16(const void* g, void* l) {
    __builtin_amdgcn_global_load_lds(
        (const __attribute__((address_space(1))) unsigned*)g,
        (__attribute__((address_space(3))) unsigned*)l,
        16, 0, 0);
}

// ---- swizzled LDS fragment read: tile layout [128 rows][128 bytes], XOR swizzle ----
__device__ __forceinline__ sv8 ldsfrag(const char* base, int row, int kc) {
    int byte = (row << 7) + (((kc << 1)) ^ ((row & 7) << 4));
    return *(const sv8*)(base + byte);
}

// =====================================================================
// prep: norms, pos_sq, d_pos (fp32 exact) + bf16 conversion of e1,e2
// grid: 4096 blocks x 128 threads  (each thread: 4 floats of one row)
// =====================================================================
__global__ __launch_bounds__(128) void prep_kernel(
    const float* __restrict__ e1, const float* __restrict__ e2,
    unsigned short* __restrict__ e1b, unsigned short* __restrict__ e2b,
    float* __restrict__ n1, float* __restrict__ n2,
    float* __restrict__ psq, float* __restrict__ dpos)
{
    const int row = blockIdx.x;
    const int t = threadIdx.x;
    const float4 a = reinterpret_cast<const float4*>(e1 + (size_t)row * 512)[t];
    const float4 b = reinterpret_cast<const float4*>(e2 + (size_t)row * 512)[t];

    ushort4 pa, pb;
    pa.x = f2bf(a.x); pa.y = f2bf(a.y); pa.z = f2bf(a.z); pa.w = f2bf(a.w);
    pb.x = f2bf(b.x); pb.y = f2bf(b.y); pb.z = f2bf(b.z); pb.w = f2bf(b.w);
    reinterpret_cast<ushort4*>(e1b + (size_t)row * 512)[t] = pa;
    reinterpret_cast<ushort4*>(e2b + (size_t)row * 512)[t] = pb;

    float s1 = a.x*a.x + a.y*a.y + a.z*a.z + a.w*a.w;
    float s2 = b.x*b.x + b.y*b.y + b.z*b.z + b.w*b.w;
    float dx = a.x-b.x, dy = a.y-b.y, dz = a.z-b.z, dw = a.w-b.w;
    float sp = dx*dx + dy*dy + dz*dz + dw*dw;

    #pragma unroll
    for (int o = 32; o; o >>= 1) {
        s1 += __shfl_down(s1, o);
        s2 += __shfl_down(s2, o);
        sp += __shfl_down(sp, o);
    }
    __shared__ float r1[2], r2[2], rp[2];
    if ((t & 63) == 0) { int wv = t >> 6; r1[wv] = s1; r2[wv] = s2; rp[wv] = sp; }
    __syncthreads();
    if (t == 0) {
        float v1 = r1[0] + r1[1];
        float v2 = r2[0] + r2[1];
        float vp = rp[0] + rp[1];
        n1[row] = v1; n2[row] = v2; psq[row] = vp; dpos[row] = sqrtf(vp);
    }
}

// =====================================================================
// main: 128x128 tile of G11=e1.e1^T, G12=e1.e2^T, G22=e2.e2^T via MFMA,
// fused hinge/count epilogue (D21 handled as transpose-term of G12).
// grid: (32,32) blocks x 512 threads (8 waves, 2x4; wave region 64x32)
// =====================================================================
__global__ __launch_bounds__(512, 2) void triplet_main(
    const unsigned short* __restrict__ e1b, const unsigned short* __restrict__ e2b,
    const float* __restrict__ n1, const float* __restrict__ n2,
    const float* __restrict__ psq, const float* __restrict__ dpos,
    float* __restrict__ total, unsigned* __restrict__ count)
{
    __shared__ char lds[65536];   // 4 tiles of [128][64] bf16 = 16KB each
    char* A1 = lds;               // e1 rows i
    char* A2 = lds + 16384;       // e2 rows i
    char* B1 = lds + 32768;       // e1 rows j
    char* B2 = lds + 49152;       // e2 rows j

    const int tid  = threadIdx.x;
    const int w    = tid >> 6;
    const int lane = tid & 63;
    const int l15  = lane & 15;
    const int l4   = lane >> 4;
    const int wr   = w >> 2;      // 0..1
    const int wc   = w & 3;       // 0..3
    const int i0   = blockIdx.y << 7;
    const int j0   = blockIdx.x << 7;

    fv4 acc11[4][2], acc12[4][2], acc22[4][2];
    #pragma unroll
    for (int m = 0; m < 4; ++m)
        #pragma unroll
        for (int n = 0; n < 2; ++n) {
            acc11[m][n] = (fv4)0.0f;
            acc12[m][n] = (fv4)0.0f;
            acc22[m][n] = (fv4)0.0f;
        }

    const char* e1c = (const char*)e1b;
    const char* e2c = (const char*)e2b;

    for (int k0 = 0; k0 < 512; k0 += 64) {
        // ---- stage 4 tiles: per thread 2 chunks per tile ----
        #pragma unroll
        for (int t = 0; t < 2; ++t) {
            const int chunk = tid + (t << 9);          // 0..1023
            const int row   = chunk >> 3;              // 0..127
            const int cb    = (chunk & 7) << 4;        // 16B slot in 128B row
            const int scb   = cb ^ ((row & 7) << 4);   // pre-swizzled source col
            const long offi = (long)(i0 + row) * 1024 + (k0 << 1) + scb;
            const long offj = (long)(j0 + row) * 1024 + (k0 << 1) + scb;
            const int lbase = ((t << 9) + (w << 6)) << 4;  // wave-uniform
            gload16(e1c + offi, A1 + lbase);
            gload16(e2c + offi, A2 + lbase);
            gload16(e1c + offj, B1 + lbase);
            gload16(e2c + offj, B2 + lbase);
        }
        __syncthreads();

        #pragma unroll
        for (int kk = 0; kk < 64; kk += 32) {
            const int kc = kk + (l4 << 3);
            sv8 a1[4], a2[4], b1[2], b2[2];
            #pragma unroll
            for (int m = 0; m < 4; ++m) {
                const int R = (wr << 6) + (m << 4) + l15;
                a1[m] = ldsfrag(A1, R, kc);
                a2[m] = ldsfrag(A2, R, kc);
            }
            #pragma unroll
            for (int n = 0; n < 2; ++n) {
                const int R = (wc << 5) + (n << 4) + l15;
                b1[n] = ldsfrag(B1, R, kc);
                b2[n] = ldsfrag(B2, R, kc);
            }
            #pragma unroll
            for (int m = 0; m < 4; ++m)
                #pragma unroll
                for (int n = 0; n < 2; ++n) {
                    acc11[m][n] = __builtin_amdgcn_mfma_f32_16x16x32_bf16(a1[m], b1[n], acc11[m][n], 0, 0, 0);
                    acc12[m][n] = __builtin_amdgcn_mfma_f32_16x16x32_bf16(a1[m], b2[n], acc12[m][n], 0, 0, 0);
                    acc22[m][n] = __builtin_amdgcn_mfma_f32_16x16x32_bf16(a2[m], b2[n], acc22[m][n], 0, 0, 0);
                }
        }
        __syncthreads();
    }

    // ---- fused epilogue: C/D layout col=lane&15, row=(lane>>4)*4+r ----
    float    ltot = 0.0f;
    unsigned lcnt = 0;

    float n1c[2], n2c[2], pc[2], dpc[2];
    #pragma unroll
    for (int n = 0; n < 2; ++n) {
        const int cc = j0 + (wc << 5) + (n << 4) + l15;
        n1c[n] = n1[cc]; n2c[n] = n2[cc]; pc[n] = psq[cc]; dpc[n] = dpos[cc];
    }

    #pragma unroll
    for (int m = 0; m < 4; ++m) {
        #pragma unroll
        for (int r = 0; r < 4; ++r) {
            const int row = i0 + (wr << 6) + (m << 4) + (l4 << 2) + r;
            const float n1r = n1[row], n2r = n2[row], pr = psq[row], dpr = dpos[row];
            #pragma unroll
            for (int n = 0; n < 2; ++n) {
                const int cc = j0 + (wc << 5) + (n << 4) + l15;
                const bool off = (row != cc);
                const float g11 = acc11[m][n][r];
                const float g12 = acc12[m][n][r];
                const float g22 = acc22[m][n][r];

                // D11 term (p[row])
                float D = fmaxf(fmaf(-2.0f, g11, n1r + n1c[n]), 0.0f);
                if (off && pr < D) { lcnt++; ltot += fmaxf(MARGIN_F + dpr - sqrtf(D), 0.0f); }

                // D12 term (p[row]) and D21 term (p[col]) share one sqrt
                float D12v = fmaxf(fmaf(-2.0f, g12, n1r + n2c[n]), 0.0f);
                float s12  = sqrtf(D12v);
                if (off && pr    < D12v) { lcnt++; ltot += fmaxf(MARGIN_F + dpr    - s12, 0.0f); }
                if (off && pc[n] < D12v) { lcnt++; ltot += fmaxf(MARGIN_F + dpc[n] - s12, 0.0f); }

                // D22 term (p[row])
                float D22v = fmaxf(fmaf(-2.0f, g22, n2r + n2c[n]), 0.0f);
                if (off && pr < D22v) { lcnt++; ltot += fmaxf(MARGIN_F + dpr - sqrtf(D22v), 0.0f); }
            }
        }
    }

    // ---- block reduction: wave shuffle -> LDS -> one atomic pair ----
    #pragma unroll
    for (int o = 32; o; o >>= 1) {
        ltot += __shfl_down(ltot, o);
        lcnt += __shfl_down(lcnt, o);
    }
    float*    lt = (float*)lds;            // LDS reuse: safe after final barrier
    unsigned* lc = (unsigned*)(lds + 64);
    if (lane == 0) { lt[w] = ltot; lc[w] = lcnt; }
    __syncthreads();
    if (tid == 0) {
        float T = 0.0f; unsigned C = 0;
        #pragma unroll
        for (int x = 0; x < 8; ++x) { T += lt[x]; C += lc[x]; }
        atomicAdd(total, T);
        atomicAdd(count, C);
    }
}

__global__ void finalize_kernel(const float* __restrict__ total,
                                const unsigned* __restrict__ count,
                                float* __restrict__ out)
{
    out[0] = total[0] / fmaxf((float)count[0], 1.0f);
}

// =====================================================================
// Workspace layout (needs ~8.6 MB):
//   [0,8)        : total (f32), count (u32)
//   [1024, ...)  : n1[4096], n2[4096], psq[4096], dpos[4096]  (f32)
//   [131072, ..) : e1b 4096x512 bf16 (4MB), then e2b (4MB)
// =====================================================================
extern "C" void kernel_launch(void* const* d_in, const int* in_sizes, int n_in,
                              void* d_out, int out_size, void* d_ws, size_t ws_size,
                              hipStream_t stream) {
    const float* e1 = (const float*)d_in[0];
    const float* e2 = (const float*)d_in[1];
    char* ws = (char*)d_ws;

    float*    total = (float*)ws;
    unsigned* count = (unsigned*)(ws + 4);
    float* n1   = (float*)(ws + 1024);
    float* n2   = n1 + 4096;
    float* psq  = n2 + 4096;
    float* dpos = psq + 4096;
    unsigned short* e1b = (unsigned short*)(ws + (1 << 17));
    unsigned short* e2b = e1b + (size_t)4096 * 512;

    hipMemsetAsync(ws, 0, 64, stream);
    prep_kernel<<<4096, 128, 0, stream>>>(e1, e2, e1b, e2b, n1, n2, psq, dpos);
    dim3 grid(32, 32);
    triplet_main<<<grid, 512, 0, stream>>>(e1b, e2b, n1, n2, psq, dpos, total, count);
    finalize_kernel<<<1, 1, 0, stream>>>(total, count, (float*)d_out);
}

// Round 2
// 95.367 us; speedup vs baseline: 1.2447x; 1.2447x over previous
//
#include <hip/hip_runtime.h>
#include <cstdint>

#define MARGIN_F 0.2f

typedef __attribute__((ext_vector_type(8))) short sv8;   // 8 x bf16 (4 VGPRs)
typedef __attribute__((ext_vector_type(4))) float fv4;   // MFMA accumulator

// ---- round-to-nearest-even fp32 -> bf16 (bit pattern) ----
__device__ __forceinline__ unsigned short f2bf(float x) {
    unsigned u = __float_as_uint(x);
    unsigned r = (u + 0x7fffu + ((u >> 16) & 1u)) >> 16;
    return (unsigned short)r;
}

// ---- async global->LDS, 16B per lane (dest = wave-uniform base + lane*16) ----
__device__ __forceinline__ void gload16(const void* g, void* l) {
    __builtin_amdgcn_global_load_lds(
        (const __attribute__((address_space(1))) unsigned*)g,
        (__attribute__((address_space(3))) unsigned*)l,
        16, 0, 0);
}

// ---- swizzled LDS fragment read: tile layout [64 rows][128 bytes], XOR swizzle ----
__device__ __forceinline__ sv8 ldsfrag(const char* base, int row, int kc) {
    int byte = (row << 7) + ((kc << 1) ^ ((row & 7) << 4));
    return *(const sv8*)(base + byte);
}

// =====================================================================
// prep: norms, pos_sq, d_pos (fp32 exact) + bf16 conversion of e1,e2
// grid: 4096 blocks x 128 threads  (each thread: 4 floats of one row)
// =====================================================================
__global__ __launch_bounds__(128) void prep_kernel(
    const float* __restrict__ e1, const float* __restrict__ e2,
    unsigned short* __restrict__ e1b, unsigned short* __restrict__ e2b,
    float* __restrict__ n1, float* __restrict__ n2,
    float* __restrict__ psq, float* __restrict__ dpos)
{
    const int row = blockIdx.x;
    const int t = threadIdx.x;
    const float4 a = reinterpret_cast<const float4*>(e1 + (size_t)row * 512)[t];
    const float4 b = reinterpret_cast<const float4*>(e2 + (size_t)row * 512)[t];

    ushort4 pa, pb;
    pa.x = f2bf(a.x); pa.y = f2bf(a.y); pa.z = f2bf(a.z); pa.w = f2bf(a.w);
    pb.x = f2bf(b.x); pb.y = f2bf(b.y); pb.z = f2bf(b.z); pb.w = f2bf(b.w);
    reinterpret_cast<ushort4*>(e1b + (size_t)row * 512)[t] = pa;
    reinterpret_cast<ushort4*>(e2b + (size_t)row * 512)[t] = pb;

    float s1 = a.x*a.x + a.y*a.y + a.z*a.z + a.w*a.w;
    float s2 = b.x*b.x + b.y*b.y + b.z*b.z + b.w*b.w;
    float dx = a.x-b.x, dy = a.y-b.y, dz = a.z-b.z, dw = a.w-b.w;
    float sp = dx*dx + dy*dy + dz*dz + dw*dw;

    #pragma unroll
    for (int o = 32; o; o >>= 1) {
        s1 += __shfl_down(s1, o);
        s2 += __shfl_down(s2, o);
        sp += __shfl_down(sp, o);
    }
    __shared__ float r1[2], r2[2], rp[2];
    if ((t & 63) == 0) { int wv = t >> 6; r1[wv] = s1; r2[wv] = s2; rp[wv] = sp; }
    __syncthreads();
    if (t == 0) {
        float v1 = r1[0] + r1[1];
        float v2 = r2[0] + r2[1];
        float vp = rp[0] + rp[1];
        n1[row] = v1; n2[row] = v2; psq[row] = vp; dpos[row] = sqrtf(vp);
    }
}

// =====================================================================
// main: pair-block scheme over 64x64 tiles, (bi<=bj) triangle.
// Off-diag block computes 4 gram tiles from one staging:
//   G11(bi,bj), G22(bi,bj)  -> emit row-term AND col-term (symmetry)
//   G12(bi,bj) = A1.B2^T    -> emit D12 row-term + D21 col-term
//   G12(bj,bi) = B1.A2^T    -> emit D12 row-term + D21 col-term
// Diag block (bi==bj): row-term-only G11/G22, G12 row+col, skip 4th.
// grid: 2080 blocks x 256 threads (4 waves, 2x2; wave region 32x32)
// =====================================================================
__global__ __launch_bounds__(256, 3) void triplet_main(
    const unsigned short* __restrict__ e1b, const unsigned short* __restrict__ e2b,
    const float* __restrict__ n1, const float* __restrict__ n2,
    const float* __restrict__ psq, const float* __restrict__ dpos,
    float* __restrict__ total, unsigned* __restrict__ count)
{
    __shared__ char lds[32768];   // 4 tiles of [64][64] bf16 = 8KB each
    char* A1 = lds;               // e1 rows bi
    char* A2 = lds + 8192;        // e2 rows bi
    char* B1 = lds + 16384;       // e1 rows bj
    char* B2 = lds + 24576;       // e2 rows bj

    // ---- triangular pair decode: bid -> (bi, bj), bi<=bj, 64 tiles/dim ----
    const int bid = blockIdx.x;
    int r = (int)((129.0f - sqrtf(16641.0f - 8.0f * (float)bid)) * 0.5f);
    // S(r) = 64r - r(r-1)/2 ; fix fp rounding
    while (64 * r - (r * (r - 1)) / 2 > bid) --r;
    while (64 * (r + 1) - ((r + 1) * r) / 2 <= bid) ++r;
    const int bi = r;
    const int bj = bi + (bid - (64 * r - (r * (r - 1)) / 2));
    const bool diag = (bi == bj);
    const int i0 = bi << 6;
    const int j0 = bj << 6;

    const int tid  = threadIdx.x;
    const int w    = tid >> 6;
    const int lane = tid & 63;
    const int l15  = lane & 15;
    const int l4   = lane >> 4;
    const int wr   = w >> 1;      // 0..1
    const int wc   = w & 1;       // 0..1

    fv4 acc11[2][2], acc22[2][2], acc12[2][2], accT[2][2];
    #pragma unroll
    for (int m = 0; m < 2; ++m)
        #pragma unroll
        for (int n = 0; n < 2; ++n) {
            acc11[m][n] = (fv4)0.0f;
            acc22[m][n] = (fv4)0.0f;
            acc12[m][n] = (fv4)0.0f;
            accT[m][n]  = (fv4)0.0f;
        }

    const char* e1c = (const char*)e1b;
    const char* e2c = (const char*)e2b;

    for (int k0 = 0; k0 < 512; k0 += 64) {
        // ---- stage 4 tiles: 8KB each, 2 chunks/thread/tile ----
        #pragma unroll
        for (int t = 0; t < 2; ++t) {
            const int chunk = tid + (t << 8);          // 0..511
            const int row   = chunk >> 3;              // 0..63
            const int cb    = (chunk & 7) << 4;        // 16B slot in 128B row
            const int scb   = cb ^ ((row & 7) << 4);   // pre-swizzled source col
            const long offi = (long)(i0 + row) * 1024 + (k0 << 1) + scb;
            const long offj = (long)(j0 + row) * 1024 + (k0 << 1) + scb;
            const int lbase = ((t << 8) + (w << 6)) << 4;  // wave-uniform
            gload16(e1c + offi, A1 + lbase);
            gload16(e2c + offi, A2 + lbase);
            gload16(e1c + offj, B1 + lbase);
            gload16(e2c + offj, B2 + lbase);
        }
        __syncthreads();

        #pragma unroll
        for (int kk = 0; kk < 64; kk += 32) {
            const int kc = kk + (l4 << 3);
            sv8 a1[2], a2[2], b1[2], b2[2];
            #pragma unroll
            for (int m = 0; m < 2; ++m) {
                const int R = (wr << 5) + (m << 4) + l15;
                a1[m] = ldsfrag(A1, R, kc);
                a2[m] = ldsfrag(A2, R, kc);
            }
            #pragma unroll
            for (int n = 0; n < 2; ++n) {
                const int R = (wc << 5) + (n << 4) + l15;
                b1[n] = ldsfrag(B1, R, kc);
                b2[n] = ldsfrag(B2, R, kc);
            }
            #pragma unroll
            for (int m = 0; m < 2; ++m)
                #pragma unroll
                for (int n = 0; n < 2; ++n) {
                    acc11[m][n] = __builtin_amdgcn_mfma_f32_16x16x32_bf16(a1[m], b1[n], acc11[m][n], 0, 0, 0);
                    acc22[m][n] = __builtin_amdgcn_mfma_f32_16x16x32_bf16(a2[m], b2[n], acc22[m][n], 0, 0, 0);
                    acc12[m][n] = __builtin_amdgcn_mfma_f32_16x16x32_bf16(a1[m], b2[n], acc12[m][n], 0, 0, 0);
                }
            if (!diag) {
                #pragma unroll
                for (int n = 0; n < 2; ++n)
                    #pragma unroll
                    for (int m = 0; m < 2; ++m)
                        accT[n][m] = __builtin_amdgcn_mfma_f32_16x16x32_bf16(b1[n], a2[m], accT[n][m], 0, 0, 0);
            }
        }
        __syncthreads();
    }

    // ---- fused epilogue: C/D layout col=lane&15, row=(lane>>4)*4+r ----
    float    ltot = 0.0f;
    unsigned lcnt = 0;
    const bool bt = !diag;   // emit symmetric col-terms for G11/G22

    // j-side columns (for acc11/acc22/acc12)
    float n1c[2], n2c[2], pc[2], dpc[2];
    #pragma unroll
    for (int n = 0; n < 2; ++n) {
        const int cc = j0 + (wc << 5) + (n << 4) + l15;
        n1c[n] = n1[cc]; n2c[n] = n2[cc]; pc[n] = psq[cc]; dpc[n] = dpos[cc];
    }
    // i-side columns (for accT)
    float n2ic[2], pic[2], dpic[2];
    #pragma unroll
    for (int m = 0; m < 2; ++m) {
        const int ic = i0 + (wr << 5) + (m << 4) + l15;
        n2ic[m] = n2[ic]; pic[m] = psq[ic]; dpic[m] = dpos[ic];
    }

    #pragma unroll
    for (int m = 0; m < 2; ++m) {
        #pragma unroll
        for (int rr = 0; rr < 4; ++rr) {
            const int row = i0 + (wr << 5) + (m << 4) + (l4 << 2) + rr;
            const float n1r = n1[row], n2r = n2[row], pr = psq[row], dpr = dpos[row];
            #pragma unroll
            for (int n = 0; n < 2; ++n) {
                const int cc = j0 + (wc << 5) + (n << 4) + l15;
                const bool off = bt || (row != cc);   // off-diag: always true

                // G11: row-term + (off-diag) col-term, shared sqrt
                float D11 = fmaxf(fmaf(-2.0f, acc11[m][n][rr], n1r + n1c[n]), 0.0f);
                float s11 = sqrtf(D11);
                if (off && pr    < D11) { lcnt++; ltot += fmaxf(MARGIN_F + dpr    - s11, 0.0f); }
                if (bt  && pc[n] < D11) { lcnt++; ltot += fmaxf(MARGIN_F + dpc[n] - s11, 0.0f); }

                // G22: same pattern
                float D22 = fmaxf(fmaf(-2.0f, acc22[m][n][rr], n2r + n2c[n]), 0.0f);
                float s22 = sqrtf(D22);
                if (off && pr    < D22) { lcnt++; ltot += fmaxf(MARGIN_F + dpr    - s22, 0.0f); }
                if (bt  && pc[n] < D22) { lcnt++; ltot += fmaxf(MARGIN_F + dpc[n] - s22, 0.0f); }

                // G12: D12 row-term (p[row]) + D21 col-term (p[col]), shared sqrt
                float D12 = fmaxf(fmaf(-2.0f, acc12[m][n][rr], n1r + n2c[n]), 0.0f);
                float s12 = sqrtf(D12);
                if (off && pr    < D12) { lcnt++; ltot += fmaxf(MARGIN_F + dpr    - s12, 0.0f); }
                if (off && pc[n] < D12) { lcnt++; ltot += fmaxf(MARGIN_F + dpc[n] - s12, 0.0f); }
            }
        }
    }

    // accT = e1[bj-rows] . e2[bi-cols]^T  (off-diag only; row!=col guaranteed)
    if (bt) {
        #pragma unroll
        for (int n = 0; n < 2; ++n) {
            #pragma unroll
            for (int rr = 0; rr < 4; ++rr) {
                const int jr = j0 + (wc << 5) + (n << 4) + (l4 << 2) + rr;
                const float n1jr = n1[jr], pjr = psq[jr], dpjr = dpos[jr];
                #pragma unroll
                for (int m = 0; m < 2; ++m) {
                    float D = fmaxf(fmaf(-2.0f, accT[n][m][rr], n1jr + n2ic[m]), 0.0f);
                    float s = sqrtf(D);
                    if (pjr    < D) { lcnt++; ltot += fmaxf(MARGIN_F + dpjr    - s, 0.0f); }
                    if (pic[m] < D) { lcnt++; ltot += fmaxf(MARGIN_F + dpic[m] - s, 0.0f); }
                }
            }
        }
    }

    // ---- block reduction: wave shuffle -> LDS -> one atomic pair ----
    #pragma unroll
    for (int o = 32; o; o >>= 1) {
        ltot += __shfl_down(ltot, o);
        lcnt += __shfl_down(lcnt, o);
    }
    float*    lt = (float*)lds;            // LDS reuse: safe after final barrier
    unsigned* lc = (unsigned*)(lds + 64);
    if (lane == 0) { lt[w] = ltot; lc[w] = lcnt; }
    __syncthreads();
    if (tid == 0) {
        float T = 0.0f; unsigned C = 0;
        #pragma unroll
        for (int x = 0; x < 4; ++x) { T += lt[x]; C += lc[x]; }
        atomicAdd(total, T);
        atomicAdd(count, C);
    }
}

__global__ void finalize_kernel(const float* __restrict__ total,
                                const unsigned* __restrict__ count,
                                float* __restrict__ out)
{
    out[0] = total[0] / fmaxf((float)count[0], 1.0f);
}

// =====================================================================
// Workspace layout (needs ~8.6 MB):
//   [0,8)        : total (f32), count (u32)
//   [1024, ...)  : n1[4096], n2[4096], psq[4096], dpos[4096]  (f32)
//   [131072, ..) : e1b 4096x512 bf16 (4MB), then e2b (4MB)
// =====================================================================
extern "C" void kernel_launch(void* const* d_in, const int* in_sizes, int n_in,
                              void* d_out, int out_size, void* d_ws, size_t ws_size,
                              hipStream_t stream) {
    const float* e1 = (const float*)d_in[0];
    const float* e2 = (const float*)d_in[1];
    char* ws = (char*)d_ws;

    float*    total = (float*)ws;
    unsigned* count = (unsigned*)(ws + 4);
    float* n1   = (float*)(ws + 1024);
    float* n2   = n1 + 4096;
    float* psq  = n2 + 4096;
    float* dpos = psq + 4096;
    unsigned short* e1b = (unsigned short*)(ws + (1 << 17));
    unsigned short* e2b = e1b + (size_t)4096 * 512;

    hipMemsetAsync(ws, 0, 64, stream);
    prep_kernel<<<4096, 128, 0, stream>>>(e1, e2, e1b, e2b, n1, n2, psq, dpos);
    triplet_main<<<2080, 256, 0, stream>>>(e1b, e2b, n1, n2, psq, dpos, total, count);
    finalize_kernel<<<1, 1, 0, stream>>>(total, count, (float*)d_out);
}